// Round 1
// baseline (711.317 us; speedup 1.0000x reference)
//
#include <hip/hip_runtime.h>
#include <hip/hip_bf16.h>

// Problem: NX=NY=8192, C1=C2=2048, D=512
//   q = x@Wq^T; k = y@Wk^T; v = y@Wv^T
//   a = mask_strict_lower(q@k^T * D^-0.5);  out = a@v   (fp32 out)
// Strategy: bf16 MFMA throughout (harness threshold 3.6 is bf16-referenced).
// ws layout (32 MB total): q[8192*512] k[8192*512] v[8192*512] vT[512*8192], all bf16.

typedef __bf16 bf16x8 __attribute__((ext_vector_type(8)));
typedef float f32x4 __attribute__((ext_vector_type(4)));

#define MFMA16(a, b, c) __builtin_amdgcn_mfma_f32_16x16x32_bf16(a, b, c, 0, 0, 0)

constexpr float SCALE = 0.04419417382415922f; // 1/sqrt(512)

__device__ inline bf16x8 pack8(float4 a, float4 b) {
    bf16x8 r;
    r[0] = (__bf16)a.x; r[1] = (__bf16)a.y; r[2] = (__bf16)a.z; r[3] = (__bf16)a.w;
    r[4] = (__bf16)b.x; r[5] = (__bf16)b.y; r[6] = (__bf16)b.z; r[7] = (__bf16)b.w;
    return r;
}

// ---------------------------------------------------------------------------
// Stage 1: C_bf16[8192,512] = A_f32[8192,2048] @ B_f32[512,2048]^T
// 128x128 tile / block, 256 thr (4 waves, each 64x64), BK=64, fp32->bf16 in staging.
// ---------------------------------------------------------------------------
__global__ __launch_bounds__(256, 2) void gemm_qkv(
    const float* __restrict__ A, const float* __restrict__ B, __bf16* __restrict__ C)
{
    constexpr int K = 2048, N = 512;
    // stride 72 elems = 144 B = 9*16B (aligned for b128) ; 36 words -> 4*row % 32 banks (2-way, free)
    __shared__ __bf16 As[128][72];
    __shared__ __bf16 Bs[128][72];

    const int tid  = threadIdx.x;
    const int wave = tid >> 6, lane = tid & 63;
    const int fr = lane & 15, fq = lane >> 4;
    const int m0 = blockIdx.x * 128;
    const int n0 = blockIdx.y * 128;
    const int wr = (wave >> 1) * 64, wc = (wave & 1) * 64;
    const int srow = tid >> 1;            // 0..127
    const int scol = (tid & 1) * 32;      // 0 or 32

    f32x4 acc[4][4];
#pragma unroll
    for (int a = 0; a < 4; ++a)
#pragma unroll
        for (int b = 0; b < 4; ++b) acc[a][b] = f32x4{0.f, 0.f, 0.f, 0.f};

    const float* ap = A + (size_t)(m0 + srow) * K + scol;
    const float* bp = B + (size_t)(n0 + srow) * K + scol;

    for (int kk = 0; kk < K; kk += 64) {
        float4 av[8], bv[8];
#pragma unroll
        for (int u = 0; u < 8; ++u) av[u] = ((const float4*)(ap + kk))[u];
#pragma unroll
        for (int u = 0; u < 8; ++u) bv[u] = ((const float4*)(bp + kk))[u];
        __syncthreads();
#pragma unroll
        for (int u = 0; u < 4; ++u) {
            *(bf16x8*)&As[srow][scol + u * 8] = pack8(av[2 * u], av[2 * u + 1]);
            *(bf16x8*)&Bs[srow][scol + u * 8] = pack8(bv[2 * u], bv[2 * u + 1]);
        }
        __syncthreads();
#pragma unroll
        for (int ks = 0; ks < 2; ++ks) {
            bf16x8 af[4], bf[4];
#pragma unroll
            for (int rt = 0; rt < 4; ++rt)
                af[rt] = *(const bf16x8*)&As[wr + rt * 16 + fr][ks * 32 + fq * 8];
#pragma unroll
            for (int nt = 0; nt < 4; ++nt)
                bf[nt] = *(const bf16x8*)&Bs[wc + nt * 16 + fr][ks * 32 + fq * 8];
#pragma unroll
            for (int rt = 0; rt < 4; ++rt)
#pragma unroll
                for (int nt = 0; nt < 4; ++nt)
                    acc[rt][nt] = MFMA16(af[rt], bf[nt], acc[rt][nt]);
        }
    }

    // C/D layout: col = lane&15, row = (lane>>4)*4 + reg
#pragma unroll
    for (int rt = 0; rt < 4; ++rt)
#pragma unroll
        for (int nt = 0; nt < 4; ++nt) {
            const int col = n0 + wc + nt * 16 + fr;
#pragma unroll
            for (int r = 0; r < 4; ++r) {
                const int row = m0 + wr + rt * 16 + fq * 4 + r;
                C[(size_t)row * N + col] = (__bf16)acc[rt][nt][r];
            }
        }
}

// ---------------------------------------------------------------------------
// Transpose v[8192,512] -> vT[512,8192] (bf16), 64x64 LDS tiles.
// ---------------------------------------------------------------------------
__global__ __launch_bounds__(256) void transpose_v(
    const ushort* __restrict__ v, ushort* __restrict__ vT)
{
    __shared__ ushort tile[64][72];
    const int t = threadIdx.x;
    const int r0 = blockIdx.x * 64;  // v row base
    const int c0 = blockIdx.y * 64;  // v col base
    const int lr = t >> 2;           // 0..63
    const int lc = (t & 3) * 16;     // 0,16,32,48

    union { float4 f[2]; ushort s[16]; } u;
    const float4* vp = (const float4*)(v + (size_t)(r0 + lr) * 512 + c0 + lc);
    u.f[0] = vp[0];
    u.f[1] = vp[1];
#pragma unroll
    for (int e = 0; e < 16; ++e) tile[lc + e][lr] = u.s[e];
    __syncthreads();
    float4* op = (float4*)(vT + (size_t)(c0 + lr) * 8192 + r0 + lc);
    op[0] = *(const float4*)&tile[lr][lc];
    op[1] = *(const float4*)&tile[lr][lc + 8];
}

// ---------------------------------------------------------------------------
// Stage 2: fused masked-score + PV.
// Block = (row-tile i of 128 rows, j-group g of 8). 512 thr = 8 waves.
// Wave w: S cols w*16..+16 (phase 1) ; O cols w*64..+64 (phase 2).
// O[128x512] fp32 held in registers across the j loop; atomicAdd epilogue.
// ---------------------------------------------------------------------------
__global__ __launch_bounds__(512, 2) void fused_av(
    const __bf16* __restrict__ q, const __bf16* __restrict__ k,
    const __bf16* __restrict__ vT, float* __restrict__ out)
{
    // ps aliases qs/ks staging space (barrier-separated) to stay < 64 KB static LDS.
    __shared__ union SM {
        struct { __bf16 qs[128][72]; __bf16 ks[128][72]; } a;
        __bf16 ps[128][136];
    } sm;

    const int tid  = threadIdx.x;
    const int wave = tid >> 6, lane = tid & 63;
    const int fr = lane & 15, fq = lane >> 4;
    const int bid = blockIdx.x;
    const int tt = bid >> 3, g = bid & 7;
    // interleave heavy (large i) and light row-tiles for balance
    const int i = (tt & 1) ? (63 - (tt >> 1)) : (tt >> 1);
    const int srow = tid >> 2;        // 0..127
    const int scol = (tid & 3) * 16;  // 0,16,32,48

    f32x4 acc_o[8][4];
#pragma unroll
    for (int rt = 0; rt < 8; ++rt)
#pragma unroll
        for (int nt = 0; nt < 4; ++nt) acc_o[rt][nt] = f32x4{0.f, 0.f, 0.f, 0.f};

    for (int j = g; j <= i; j += 8) {
        // ---- phase 1: S = Q_i @ K_j^T  (128x128, K=512) ----
        f32x4 acc_s[8];
#pragma unroll
        for (int rt = 0; rt < 8; ++rt) acc_s[rt] = f32x4{0.f, 0.f, 0.f, 0.f};

        for (int kk = 0; kk < 512; kk += 64) {
            const float4* qp = (const float4*)(q + (size_t)(i * 128 + srow) * 512 + kk + scol);
            const float4* kp = (const float4*)(k + (size_t)(j * 128 + srow) * 512 + kk + scol);
            float4 qv0 = qp[0], qv1 = qp[1];
            float4 kv0 = kp[0], kv1 = kp[1];
            __syncthreads();  // prior readers of qs/ks (and ps reads of prev j) done
            *(float4*)&sm.a.qs[srow][scol]     = qv0;
            *(float4*)&sm.a.qs[srow][scol + 8] = qv1;
            *(float4*)&sm.a.ks[srow][scol]     = kv0;
            *(float4*)&sm.a.ks[srow][scol + 8] = kv1;
            __syncthreads();
#pragma unroll
            for (int ks = 0; ks < 2; ++ks) {
                bf16x8 bfr = *(const bf16x8*)&sm.a.ks[wave * 16 + fr][ks * 32 + fq * 8];
#pragma unroll
                for (int rt = 0; rt < 8; ++rt) {
                    bf16x8 afr = *(const bf16x8*)&sm.a.qs[rt * 16 + fr][ks * 32 + fq * 8];
                    acc_s[rt] = MFMA16(afr, bfr, acc_s[rt]);
                }
            }
        }

        __syncthreads();  // all qs/ks reads done before ps (aliased) writes
        // ---- mask + scale -> P (bf16) in LDS ----
        {
            const int col = wave * 16 + fr;
            const int gcol = j * 128 + col;
#pragma unroll
            for (int rt = 0; rt < 8; ++rt) {
                const int rowb = rt * 16 + fq * 4;
#pragma unroll
                for (int r = 0; r < 4; ++r) {
                    const int grow = i * 128 + rowb + r;
                    float s = acc_s[rt][r] * SCALE;
                    sm.ps[rowb + r][col] = (__bf16)((gcol >= grow) ? 0.f : s);
                }
            }
        }
        __syncthreads();

        // ---- phase 2: O += P @ V_j  (B-fragments straight from global vT) ----
#pragma unroll
        for (int ks2 = 0; ks2 < 4; ++ks2) {
            bf16x8 bfr[4];
#pragma unroll
            for (int nt = 0; nt < 4; ++nt)
                bfr[nt] = *(const bf16x8*)(vT + (size_t)(wave * 64 + nt * 16 + fr) * 8192
                                           + j * 128 + ks2 * 32 + fq * 8);
#pragma unroll
            for (int rt = 0; rt < 8; ++rt) {
                bf16x8 afr = *(const bf16x8*)&sm.ps[rt * 16 + fr][ks2 * 32 + fq * 8];
#pragma unroll
                for (int nt = 0; nt < 4; ++nt)
                    acc_o[rt][nt] = MFMA16(afr, bfr[nt], acc_o[rt][nt]);
            }
        }
        // next j's first __syncthreads() separates these ps reads from qs writes
    }

    if (g <= i) {  // blocks with no j-iterations contribute nothing
#pragma unroll
        for (int rt = 0; rt < 8; ++rt)
#pragma unroll
            for (int nt = 0; nt < 4; ++nt) {
                const int col = wave * 64 + nt * 16 + fr;
#pragma unroll
                for (int r = 0; r < 4; ++r) {
                    const int row = i * 128 + rt * 16 + fq * 4 + r;
                    atomicAdd(&out[(size_t)row * 512 + col], acc_o[rt][nt][r]);
                }
            }
    }
}

// ---------------------------------------------------------------------------
extern "C" void kernel_launch(void* const* d_in, const int* in_sizes, int n_in,
                              void* d_out, int out_size, void* d_ws, size_t ws_size,
                              hipStream_t stream) {
    const float* x  = (const float*)d_in[0];
    const float* y  = (const float*)d_in[1];
    const float* Wq = (const float*)d_in[2];
    const float* Wk = (const float*)d_in[3];
    const float* Wv = (const float*)d_in[4];
    float* out = (float*)d_out;

    const size_t QK = (size_t)8192 * 512;
    __bf16* q  = (__bf16*)d_ws;
    __bf16* k  = q + QK;
    __bf16* v  = k + QK;
    __bf16* vT = v + QK;

    hipMemsetAsync(d_out, 0, QK * sizeof(float), stream);

    dim3 bg(64, 4);
    gemm_qkv<<<bg, 256, 0, stream>>>(x, Wq, q);
    gemm_qkv<<<bg, 256, 0, stream>>>(y, Wk, k);
    gemm_qkv<<<bg, 256, 0, stream>>>(y, Wv, v);
    transpose_v<<<dim3(128, 8), 256, 0, stream>>>((const ushort*)v, (ushort*)vT);
    fused_av<<<512, 512, 0, stream>>>(q, k, vT, out);
}